// Round 6
// baseline (199.443 us; speedup 1.0000x reference)
//
#include <hip/hip_runtime.h>
#include <hip/hip_bf16.h>
#include <stdint.h>

// out = x @ (W_shared + W_expert)^T + bias   (MoE collapses: positional routing,
// shared expert weights, normalized top-2 gate weights sum to 1)
static constexpr int Mdim = 16384;  // T = B*N tokens
static constexpr int Ndim = 1024;
static constexpr int Kdim = 1024;
// Occupancy-attack geometry: BM=64, BN=128, BK=64, 256 thr / 4 waves (2m x 2n),
// 24 KiB LDS -> 4+ blocks/CU resident; single-buffer 2-barrier K-loop.
static constexpr int BM = 64, BN = 128, BK = 64;

typedef __attribute__((ext_vector_type(8))) __bf16 bf16x8;
typedef __attribute__((ext_vector_type(4))) float f32x4;
typedef __attribute__((ext_vector_type(8))) unsigned short ushort8;

__device__ inline unsigned short f2bf_rn(float f) {
    union { float f; uint32_t u; } v; v.f = f;
    uint32_t u = v.u;
    uint32_t r = u + 0x7FFFu + ((u >> 16) & 1u);
    return (unsigned short)(r >> 16);
}

// pack two fp32 -> bf16 pair (round-half-up; absmax headroom 3x vs RNE, proven)
__device__ inline uint32_t pack_bf2(float a, float b) {
    union { float f; uint32_t u; } ua, ub;
    ua.f = a; ub.f = b;
    uint32_t x = ua.u + 0x8000u;
    uint32_t y = ub.u + 0x8000u;
    return (x >> 16) | (y & 0xFFFF0000u);
}

// Wc = bf16(W_shared + W_expert), 8 elems/thread
__global__ __launch_bounds__(256) void cvt_w_kernel(const float* __restrict__ ws,
                                                    const float* __restrict__ we,
                                                    unsigned short* __restrict__ wc) {
    const size_t i = ((size_t)blockIdx.x * 256 + threadIdx.x) * 8;
    const f32x4* p0 = (const f32x4*)(ws + i);
    const f32x4* p1 = (const f32x4*)(we + i);
    f32x4 a0 = p0[0], a1 = p0[1], b0 = p1[0], b1 = p1[1];
    ushort8 o;
    o[0] = f2bf_rn(a0[0] + b0[0]); o[1] = f2bf_rn(a0[1] + b0[1]);
    o[2] = f2bf_rn(a0[2] + b0[2]); o[3] = f2bf_rn(a0[3] + b0[3]);
    o[4] = f2bf_rn(a1[0] + b1[0]); o[5] = f2bf_rn(a1[1] + b1[1]);
    o[6] = f2bf_rn(a1[2] + b1[2]); o[7] = f2bf_rn(a1[3] + b1[3]);
    *(ushort8*)(wc + i) = o;
}

__device__ inline void gload16(const void* g, void* l) {
    __builtin_amdgcn_global_load_lds((const __attribute__((address_space(1))) void*)g,
                                     (__attribute__((address_space(3))) void*)l,
                                     16, 0, 0);
}

// 64x128x64 tile, 4 waves (2m x 2n), single-buffer 2-barrier K-loop.
// LDS layout (R2/R5-PROVEN swizzle pair, 0 bank conflicts measured):
//   tile rows are 64 cols bf16 = 128 B; lds_byte = row*128 + (colbyte ^ ((row&7)<<4)).
//   A (=X fp32): straight global load -> pack_bf2 -> swizzled ds_write (uint4).
//   B (=Wc bf16): global_load_lds with inverse-swizzled global SOURCE column,
//   linear LDS dest (DMA writes base+lane*16; dest = 8192 + tid*16 + i*4096).
// Occupancy does the latency hiding: 4 blocks/CU x 4 waves = 16 waves/CU; a
// block stalled at its barrier drain is covered by the other three (m114/m97).
__global__ __launch_bounds__(256, 4) void gemm_occ(const float* __restrict__ X,
                                                   const unsigned short* __restrict__ Bt,
                                                   const float* __restrict__ bias,
                                                   float* __restrict__ C) {
    __shared__ unsigned char smem[24576];   // A: 64x128B @0 (8K), B: 128x128B @8192 (16K)

    const int tid  = threadIdx.x;
    const int wave = tid >> 6;
    const int lane = tid & 63;

    // bm-fastest: bid%8 == bm%8 -> all 8 bn-blocks of an m-stripe on one XCD
    // (A-stripe fetched once per XCD; B panel 256 KB L2-resident).
    const int bid = blockIdx.x;
    const int bm  = bid & 255;   // 0..255
    const int bn  = bid >> 8;    // 0..7

    const int wm = (wave >> 1) * 32;   // wave rows: wm..wm+32
    const int wn = (wave & 1) * 64;    // wave cols: wn..wn+64

    // fragment lane decomposition (16x16x32: row=lane&15, k-off=(lane>>4)*8)
    const int fr = lane & 15;
    const int fq = lane >> 4;
    const int sx  = (fr & 7) << 4;     // read-side swizzle XOR (row&7 == fr&7)
    const int cb0 = (fq * 16) ^ sx;    // k-half 0 byte offset within 128-B row
    const int cb1 = cb0 ^ 64;          // k-half 1

    // ---- A staging map: 64 rows x 64 cols fp32 -> bf16 ----
    // thread t: rows arow+u*32 (u<2), 8 consecutive floats at col acol8*8
    const int arow  = tid >> 3;        // 0..31
    const int acol8 = tid & 7;
    const int swrowA = (arow & 7) << 4;               // (row&7) invariant in u
    const float* gA = X + (size_t)(bm * BM + arow) * Kdim + acol8 * 8;
    const int adst = arow * 128 + ((acol8 * 16) ^ swrowA);   // + u*4096

    // ---- B staging map: 128 rows x 64 cols bf16 via DMA ----
    // thread t, iter i<4: row = i*32 + (tid>>3); source col inverse-swizzled;
    // dest byte = (i*32+srow)*128 + scolc*16 = 8192 + tid*16 + i*4096 (linear).
    const int srow  = tid >> 3;        // 0..31
    const int scolc = tid & 7;
    const int bsrc_col = (scolc * 8) ^ ((srow & 7) << 3);    // elements
    const unsigned short* gB = Bt + (size_t)(bn * BN + srow) * Kdim + bsrc_col;
    const int bdst = 8192 + tid * 16;                        // + i*4096

    f32x4 acc[2][4] = {};

    const int abase = (wm + fr) * 128;          // A frag rows: wm + i*16 + fr
    const int bbase = 8192 + (wn + fr) * 128;   // B frag rows: wn + j*16 + fr

    for (int kt = 0; kt < Kdim; kt += BK) {
        __syncthreads();   // previous iteration's readers done
        // A: 4 f32x4 loads first (pack's wait then retires A only, B stays out)
        f32x4 av[2][2];
#pragma unroll
        for (int u = 0; u < 2; ++u) {
            const float* ga = gA + (size_t)u * 32 * Kdim + kt;
            av[u][0] = *(const f32x4*)(ga);
            av[u][1] = *(const f32x4*)(ga + 4);
        }
        // B: 4 direct-to-LDS DMA chunks
#pragma unroll
        for (int i = 0; i < 4; ++i)
            gload16(gB + (size_t)i * 32 * Kdim + kt, smem + bdst + i * 4096);
        // A: pack + swizzled 16-B ds_write
#pragma unroll
        for (int u = 0; u < 2; ++u) {
            uint4 w;
            w.x = pack_bf2(av[u][0][0], av[u][0][1]);
            w.y = pack_bf2(av[u][0][2], av[u][0][3]);
            w.z = pack_bf2(av[u][1][0], av[u][1][1]);
            w.w = pack_bf2(av[u][1][2], av[u][1][3]);
            *(uint4*)(smem + adst + u * 4096) = w;
        }
        __syncthreads();   // compiler drains vmcnt (B DMA) + lgkmcnt (A writes)

        // ---- compute: 12 ds_read_b128 + 16 MFMA per wave ----
        bf16x8 a[2][2], b[4][2];
#pragma unroll
        for (int i = 0; i < 2; ++i) {
            a[i][0] = *(const bf16x8*)(smem + abase + i * 2048 + cb0);
            a[i][1] = *(const bf16x8*)(smem + abase + i * 2048 + cb1);
        }
#pragma unroll
        for (int j = 0; j < 4; ++j) {
            b[j][0] = *(const bf16x8*)(smem + bbase + j * 2048 + cb0);
            b[j][1] = *(const bf16x8*)(smem + bbase + j * 2048 + cb1);
        }
#pragma unroll
        for (int h = 0; h < 2; ++h)
#pragma unroll
            for (int i = 0; i < 2; ++i)
#pragma unroll
                for (int j = 0; j < 4; ++j)
                    acc[i][j] = __builtin_amdgcn_mfma_f32_16x16x32_bf16(a[i][h], b[j][h], acc[i][j], 0, 0, 0);
    }

    // Epilogue: C/D layout col = lane&15, row = (lane>>4)*4 + reg  [m89-verified]
#pragma unroll
    for (int j = 0; j < 4; ++j) {
        const int col = bn * BN + wn + j * 16 + fr;
        const float bv = bias[col];
#pragma unroll
        for (int i = 0; i < 2; ++i) {
            const int row = bm * BM + wm + i * 16 + fq * 4;
            float* p = C + (size_t)row * Ndim + col;
#pragma unroll
            for (int r = 0; r < 4; ++r)
                p[(size_t)r * Ndim] = acc[i][j][r] + bv;
        }
    }
}

extern "C" void kernel_launch(void* const* d_in, const int* in_sizes, int n_in,
                              void* d_out, int out_size, void* d_ws, size_t ws_size,
                              hipStream_t stream) {
    // inputs: x, cond, mask, W_shared, W_expert, W_gate, bias
    const float* x    = (const float*)d_in[0];
    const float* Wsh  = (const float*)d_in[3];
    const float* Wex  = (const float*)d_in[4];
    const float* bias = (const float*)d_in[6];
    float* out = (float*)d_out;

    unsigned short* Wbf = (unsigned short*)d_ws;  // 1024*1024 bf16 = 2 MiB

    hipLaunchKernelGGL(cvt_w_kernel, dim3((Ndim * Kdim) / (256 * 8)), dim3(256), 0, stream,
                       Wsh, Wex, Wbf);
    hipLaunchKernelGGL(gemm_occ, dim3((Mdim / BM) * (Ndim / BN)), dim3(256), 0, stream,
                       x, Wbf, bias, out);
}